// Round 9
// baseline (231.240 us; speedup 1.0000x reference)
//
#include <hip/hip_runtime.h>
#include <hip/hip_bf16.h>

typedef __bf16 bf16;
typedef __bf16 bf16x8 __attribute__((ext_vector_type(8)));
typedef __bf16 bf16x4 __attribute__((ext_vector_type(4)));
typedef float  f32x4  __attribute__((ext_vector_type(4)));

#define MFMA16(A, B, C) __builtin_amdgcn_mfma_f32_16x16x32_bf16((A), (B), (C), 0, 0, 0)

static constexpr int Bn = 4;
static constexpr int T  = 4096;
static constexpr int Cd = 1024;
static constexpr int H  = 64;
static constexpr int NG = 192;
static constexpr int CH = 8;             // K-tiles (64 keys) per chunk = 512 keys
static constexpr int SLOTS_PER_B = 1152; // sum_{r=0..255} ((r>>5)+1)
static constexpr float QSCALE = 0.03125f;

// async global->LDS DMA, 16B per lane; LDS dest = wave-uniform base + lane*16
__device__ inline void dma16(const void* g, void* l) {
    __builtin_amdgcn_global_load_lds(
        (const __attribute__((address_space(1))) unsigned int*)g,
        (__attribute__((address_space(3))) unsigned int*)l, 16, 0, 0);
}

__device__ inline bf16x8 cvt_bf16x8(float4 a, float4 b) {
    bf16x8 r;
    r[0] = (bf16)a.x; r[1] = (bf16)a.y; r[2] = (bf16)a.z; r[3] = (bf16)a.w;
    r[4] = (bf16)b.x; r[5] = (bf16)b.y; r[6] = (bf16)b.z; r[7] = (bf16)b.w;
    return r;
}

// ---------------------------------------------------------------------------
// Kernel 1: coalesced transpose W=[Wq|Wk|Wv] ([C][H] fp32) -> Wt[192][1024] bf16
// ---------------------------------------------------------------------------
__global__ __launch_bounds__(256) void wt_kernel(const float* __restrict__ Wq,
                                                 const float* __restrict__ Wk,
                                                 const float* __restrict__ Wv,
                                                 bf16* __restrict__ Wt) {
    __shared__ float s[64][65];
    const int cb = blockIdx.x;
    const int m  = blockIdx.y;
    const float* W = (m == 0) ? Wq : (m == 1) ? Wk : Wv;
    for (int i = threadIdx.x; i < 64 * 64; i += 256) {
        const int c = i >> 6, h = i & 63;
        s[c][h] = W[(cb * 64 + c) * H + h];
    }
    __syncthreads();
    for (int i = threadIdx.x; i < 64 * 64; i += 256) {
        const int n = i >> 6, c = i & 63;
        Wt[(m * 64 + n) * Cd + cb * 64 + c] = (bf16)s[c][n];
    }
}

// ---------------------------------------------------------------------------
// Kernel 2: QKV projection (R6 v6, best known). grid = M/32 = 512 blocks,
// 512 thr = 8 waves (2x4). x AND Wt staged via DMA, double-buffered, swizzled.
// ---------------------------------------------------------------------------
__global__ __launch_bounds__(512, 4) void proj_kernel(const float* __restrict__ x,
                                                      const bf16* __restrict__ Wt,
                                                      bf16* __restrict__ qw,
                                                      bf16* __restrict__ kw,
                                                      bf16* __restrict__ vtw) {
    const int tid  = threadIdx.x;
    const int lane = tid & 63;
    const int w    = tid >> 6;
    const int wr   = w >> 2;
    const int wc   = w & 3;
    const int ml   = lane & 15;
    const int quad = lane >> 4;

    const long r0 = (long)blockIdx.x * 32;

    __shared__ float sX[2][32][64];
    __shared__ bf16  sW[2][192][64];

    const int xrow = w * 4 + (lane >> 4);
    const float* gx = x + (r0 + xrow) * Cd + (((lane & 15) ^ (xrow & 15)) << 2);
    const int wchunk = ((lane & 7) ^ (lane >> 3)) << 3;
    const bf16* gw0 = Wt + (long)(w * 24 + 0 + (lane >> 3)) * Cd + wchunk;
    const bf16* gw1 = Wt + (long)(w * 24 + 8 + (lane >> 3)) * Cd + wchunk;
    const bf16* gw2 = Wt + (long)(w * 24 + 16 + (lane >> 3)) * Cd + wchunk;

    f32x4 acc[3];
    #pragma unroll
    for (int j = 0; j < 3; ++j) acc[j] = f32x4{0.f, 0.f, 0.f, 0.f};

    dma16(gx, &sX[0][w * 4][0]);
    dma16(gw0, &sW[0][w * 24 + 0][0]);
    dma16(gw1, &sW[0][w * 24 + 8][0]);
    dma16(gw2, &sW[0][w * 24 + 16][0]);
    __syncthreads();

    const int arow = wr * 16 + ml;
    const int brow0 = wc * 48 + ml;
    const int bsw = ml & 7;

    int buf = 0;
    for (int kb = 0; kb < Cd; kb += 64) {
        if (kb + 64 < Cd) {
            dma16(gx + kb + 64, &sX[buf ^ 1][w * 4][0]);
            dma16(gw0 + kb + 64, &sW[buf ^ 1][w * 24 + 0][0]);
            dma16(gw1 + kb + 64, &sW[buf ^ 1][w * 24 + 8][0]);
            dma16(gw2 + kb + 64, &sW[buf ^ 1][w * 24 + 16][0]);
        }

        #pragma unroll
        for (int ks = 0; ks < 2; ++ks) {
            const int ca = (ks * 8 + quad * 2) ^ ml;
            const float4 lo = *(const float4*)&sX[buf][arow][ca << 2];
            const float4 hi = *(const float4*)&sX[buf][arow][(ca ^ 1) << 2];
            const bf16x8 af = cvt_bf16x8(lo, hi);
            const int cb0 = (ks * 4 + quad) ^ bsw;
            acc[0] = MFMA16(af, *(const bf16x8*)&sW[buf][brow0 + 0][cb0 << 3], acc[0]);
            acc[1] = MFMA16(af, *(const bf16x8*)&sW[buf][brow0 + 16][cb0 << 3], acc[1]);
            acc[2] = MFMA16(af, *(const bf16x8*)&sW[buf][brow0 + 32][cb0 << 3], acc[2]);
        }

        __syncthreads();
        buf ^= 1;
    }

    const int b = (int)(r0 >> 12);
    const long rowb = r0 + wr * 16 + quad * 4;
    const int  tloc = (int)(rowb & 4095);

    #pragma unroll
    for (int f = 0; f < 3; ++f) {
        const int base = wc * 48 + f * 16;
        const int sel  = base >> 6;
        const int h    = (base & 63) + ml;
        if (sel == 0) {
            #pragma unroll
            for (int rr = 0; rr < 4; ++rr)
                qw[(rowb + rr) * H + h] = (bf16)(acc[f][rr] * QSCALE);
        } else if (sel == 1) {
            #pragma unroll
            for (int rr = 0; rr < 4; ++rr)
                kw[(rowb + rr) * H + h] = (bf16)acc[f][rr];
        } else {
            bf16x4 pv;
            #pragma unroll
            for (int rr = 0; rr < 4; ++rr) pv[rr] = (bf16)acc[f][rr];
            *(bf16x4*)(vtw + ((long)(b * H + h)) * T + tloc) = pv;
        }
    }
}

// ---------------------------------------------------------------------------
// Kernel 3: barrier-free wave-independent flash chunk. Each wave: 16 Q-rows x
// one 512-key chunk. K/V frags direct from global (L2-resident); only LDS is
// the wave-private padded sP (no __syncthreads in the kernel).
// grid (64, 8, 4), 256 thr; block early-exits uniformly when chunk unused.
// rowgroup r = bx*4+w; chunks for r: (r>>5)+1 (uniform within block).
// ---------------------------------------------------------------------------
__global__ __launch_bounds__(256) void attn_kernel(const bf16* __restrict__ qw,
                                                   const bf16* __restrict__ kw,
                                                   const bf16* __restrict__ vtw,
                                                   float* __restrict__ pO,
                                                   float* __restrict__ pL) {
    const int bx = blockIdx.x;
    const int c  = blockIdx.y;
    const int b  = blockIdx.z;
    const int kblk = (bx >> 3) + 1;      // chunks for all 4 rowgroups in block
    if (c >= kblk) return;               // uniform early exit

    const int tid  = threadIdx.x;
    const int lane = tid & 63;
    const int w    = tid >> 6;
    const int ml   = lane & 15;
    const int quad = lane >> 4;

    const int r  = bx * 4 + w;           // wave's 16-row group, 0..255
    const int t0 = r * 16;

    __shared__ bf16 sP[4][16][72];       // wave-private

    const bf16* qb = qw + ((long)b * T + t0 + ml) * H;
    const bf16x8 aq0 = *(const bf16x8*)(qb + quad * 8);
    const bf16x8 aq1 = *(const bf16x8*)(qb + 32 + quad * 8);

    f32x4 O[4];
    #pragma unroll
    for (int ht = 0; ht < 4; ++ht) O[ht] = f32x4{0.f, 0.f, 0.f, 0.f};
    float lrow[4] = {0.f, 0.f, 0.f, 0.f};

    const int jdiag = r >> 2;
    const int jt0   = c * CH;
    const int jtmax = jdiag + 1;
    const int jt1   = (jt0 + CH < jtmax) ? jt0 + CH : jtmax;

    const bf16* kbase = kw + (long)b * T * H;
    const bf16* vbase = vtw + (long)b * H * T;

    for (int jt = jt0; jt < jt1; ++jt) {
        const int s0 = jt * 64;
        const bool diag = (jt == jdiag);

        #pragma unroll
        for (int nt = 0; nt < 4; ++nt) {
            const bf16* kr = kbase + (long)(s0 + nt * 16 + ml) * H + quad * 8;
            f32x4 sacc = f32x4{0.f, 0.f, 0.f, 0.f};
            sacc = MFMA16(aq0, *(const bf16x8*)(kr), sacc);
            sacc = MFMA16(aq1, *(const bf16x8*)(kr + 32), sacc);
            const int col = s0 + nt * 16 + ml;
            #pragma unroll
            for (int rr = 0; rr < 4; ++rr) {
                const float p = (diag && col > t0 + quad * 4 + rr) ? 0.f : __expf(sacc[rr]);
                lrow[rr] += p;
                sP[w][quad * 4 + rr][nt * 16 + ml] = (bf16)p;
            }
        }
        asm volatile("s_waitcnt lgkmcnt(0)" ::: "memory");  // wave-private sP RAW

        #pragma unroll
        for (int ks = 0; ks < 2; ++ks) {
            const bf16x8 ap = *(const bf16x8*)&sP[w][ml][ks * 32 + quad * 8];
            #pragma unroll
            for (int ht = 0; ht < 4; ++ht) {
                const bf16x8 bv = *(const bf16x8*)(vbase + (long)(ht * 16 + ml) * T
                                                   + s0 + ks * 32 + quad * 8);
                O[ht] = MFMA16(ap, bv, O[ht]);
            }
        }
    }

    #pragma unroll
    for (int d = 1; d < 16; d <<= 1)
        #pragma unroll
        for (int rr = 0; rr < 4; ++rr)
            lrow[rr] += __shfl_xor(lrow[rr], d, 64);

    const int G = r >> 5;
    const long slot = (long)b * SLOTS_PER_B + 16 * G * (G + 1) + (long)(r & 31) * (G + 1) + c;
    float* po = pO + slot * 1024;
    #pragma unroll
    for (int ht = 0; ht < 4; ++ht)
        #pragma unroll
        for (int rr = 0; rr < 4; ++rr)
            po[(quad * 4 + rr) * 64 + ht * 16 + ml] = O[ht][rr];
    if (ml == 0) {
        #pragma unroll
        for (int rr = 0; rr < 4; ++rr)
            pL[slot * 16 + quad * 4 + rr] = lrow[rr];
    }
}

// ---------------------------------------------------------------------------
// Kernel 4: combine partials. grid (256 rowgroups, 4 b), 256 thr
// (16 rows x 16 thr x f32x4).
// ---------------------------------------------------------------------------
__global__ __launch_bounds__(256) void combine_kernel(const float* __restrict__ pO,
                                                      const float* __restrict__ pL,
                                                      float* __restrict__ out) {
    const int r = blockIdx.x;
    const int b = blockIdx.y;
    const int G = r >> 5;
    const int k = G + 1;
    const long slot0 = (long)b * SLOTS_PER_B + 16 * G * (G + 1) + (long)(r & 31) * k;

    const int tid = threadIdx.x;
    const int row = tid >> 4;        // 0..15
    const int c4  = (tid & 15) * 4;

    f32x4 o = f32x4{0.f, 0.f, 0.f, 0.f};
    float l = 0.f;
    for (int cc = 0; cc < k; ++cc) {
        o += *(const f32x4*)(pO + (slot0 + cc) * 1024 + row * 64 + c4);
        l += pL[(slot0 + cc) * 16 + row];
    }
    const float inv = 1.f / l;
    f32x4 v = o;
    v[0] *= inv; v[1] *= inv; v[2] *= inv; v[3] *= inv;
    *(f32x4*)(out + ((long)b * T + r * 16 + row) * H + c4) = v;
}

// ---------------------------------------------------------------------------
extern "C" void kernel_launch(void* const* d_in, const int* in_sizes, int n_in,
                              void* d_out, int out_size, void* d_ws, size_t ws_size,
                              hipStream_t stream) {
    const float* x  = (const float*)d_in[0];
    const float* Wq = (const float*)d_in[1];
    const float* Wk = (const float*)d_in[2];
    const float* Wv = (const float*)d_in[3];
    float* out = (float*)d_out;

    char* ws = (char*)d_ws;
    const size_t WT_BYTES = (size_t)NG * Cd * sizeof(bf16);
    const size_t QK_BYTES = (size_t)Bn * T * H * sizeof(bf16);
    const size_t PO_OFF   = WT_BYTES + 3 * QK_BYTES;
    const size_t PO_BYTES = (size_t)Bn * SLOTS_PER_B * 1024 * sizeof(float); // 18.9 MiB
    bf16*  Wt  = (bf16*)ws;
    bf16*  qw  = (bf16*)(ws + WT_BYTES);
    bf16*  kw  = (bf16*)(ws + WT_BYTES + QK_BYTES);
    bf16*  vtw = (bf16*)(ws + WT_BYTES + 2 * QK_BYTES);
    float* pO  = (float*)(ws + PO_OFF);
    float* pL  = (float*)(ws + PO_OFF + PO_BYTES);

    wt_kernel<<<dim3(16, 3), dim3(256), 0, stream>>>(Wq, Wk, Wv, Wt);
    proj_kernel<<<dim3((Bn * T) / 32), dim3(512), 0, stream>>>(x, Wt, qw, kw, vtw);
    attn_kernel<<<dim3(64, CH, Bn), dim3(256), 0, stream>>>(qw, kw, vtw, pO, pL);
    combine_kernel<<<dim3(256, Bn), dim3(256), 0, stream>>>(pO, pL, out);
}